// Round 12
// baseline (322.504 us; speedup 1.0000x reference)
//
#include <hip/hip_runtime.h>

// GraphConv x2, CSR-pull + f16 MFMA GEMMs (R12):
//   wcast -> f16 ; xcast_sliced -> xs[8][N][16] SLICE-MAJOR f16
//   CSR build: atomic-free 2-level counting sort (R11, unchanged)
//   pull_sliced: aggs[s][n][16] = sum xs[s][srcs][16], slice s = blockIdx&7
//     -> each XCD gathers only from its own 3.2 MB slice (L2-resident)
//   mfma_gemm1: h(f16,row-major) = relu(aggs@Wr1^T + xs@Wq1^T + b1)
//   mfma_gemm2: hr(f16) = h@Wr2^T ; out(f32) = h@Wq2^T + b2
//   pull_add_h64: out += sum hr[srcs]   (unchanged)
//
// R12 rationale: pull_h128 top (62us, FETCH 177MB, 3.3TB/s fetch path).
// 409MB logical / 62us = 6.6TB/s delivered with 43% L2 miss — xh (25.6MB)
// exceeds the 4MB per-XCD L2, random gather from all 256 CUs. fp8 would halve
// bytes but 6% rel err blows the 0.93 absmax budget. Instead: feature-slice
// the table per XCD (slice-major layout + slice=blockIdx&7, using the
// round-robin blockIdx->XCD dispatch) so each XCD's gather working set is
// 3.2MB -> private-L2 resident. FETCH should drop to ~compulsory+srcs.

typedef float f4 __attribute__((ext_vector_type(4)));
typedef _Float16 h8 __attribute__((ext_vector_type(8)));
typedef _Float16 h2 __attribute__((ext_vector_type(2)));

#define NB   1024    // coarse buckets (dst>>7); requires N <= 131072
#define EPB  4096    // edges per block in s1/s3; nblk = ceil(E/EPB) <= 512

__device__ __forceinline__ float2 h2f(unsigned u) {
    h2 p = __builtin_bit_cast(h2, u);
    float2 r; r.x = (float)p[0]; r.y = (float)p[1];
    return r;
}
__device__ __forceinline__ unsigned f2h(float a, float b) {
    h2 p; p[0] = (_Float16)a; p[1] = (_Float16)b;
    return __builtin_bit_cast(unsigned, p);
}

// ---------------------------- casts ----------------------------------------
// wbuf layout (halves): wr1h @0 [128x128] | wq1h @16384 | wr2h @32768 [64x128]
// | wq2h @40960  (total 49152)
__global__ void wcast(const float* __restrict__ wr1, const float* __restrict__ wq1,
                      const float* __restrict__ wr2, const float* __restrict__ wq2,
                      _Float16* __restrict__ wb)
{
    int i = blockIdx.x * 256 + threadIdx.x;
    if (i < 16384)      wb[i] = (_Float16)wr1[i];
    else if (i < 32768) wb[i] = (_Float16)wq1[i - 16384];
    else if (i < 40960) wb[i] = (_Float16)wr2[i - 32768];
    else if (i < 49152) wb[i] = (_Float16)wq2[i - 40960];
}

// x row-major -> xs slice-major: xs[s][node][16], s = feat>>4.
// thread i = s*N + node: reads 16 f32 (64B strided), writes 32B coalesced.
__global__ void xcast_sliced(const float* __restrict__ x, _Float16* __restrict__ xs,
                             int N)
{
    long i = blockIdx.x * 256 + threadIdx.x;
    if (i >= (long)N * 8) return;
    int s = (int)(i / N);
    int node = (int)(i - (long)s * N);
    const float* p = x + (size_t)node * 128 + s * 16;
    h8 o0, o1;
    f4 a = *(const f4*)(p);
    f4 b = *(const f4*)(p + 4);
    f4 c = *(const f4*)(p + 8);
    f4 d = *(const f4*)(p + 12);
    o0[0] = (_Float16)a[0]; o0[1] = (_Float16)a[1];
    o0[2] = (_Float16)a[2]; o0[3] = (_Float16)a[3];
    o0[4] = (_Float16)b[0]; o0[5] = (_Float16)b[1];
    o0[6] = (_Float16)b[2]; o0[7] = (_Float16)b[3];
    o1[0] = (_Float16)c[0]; o1[1] = (_Float16)c[1];
    o1[2] = (_Float16)c[2]; o1[3] = (_Float16)c[3];
    o1[4] = (_Float16)d[0]; o1[5] = (_Float16)d[1];
    o1[6] = (_Float16)d[2]; o1[7] = (_Float16)d[3];
    _Float16* q = xs + i * 16;
    *(h8*)(q) = o0;
    *(h8*)(q + 8) = o1;
}

// ------------------ CSR build: atomic-free counting sort --------------------
__global__ __launch_bounds__(256) void s1_hist(const int* __restrict__ dst,
                                               int* __restrict__ mat, int E)
{
    __shared__ int hist[NB];
    const int tid = threadIdx.x;
    for (int i = tid; i < NB; i += 256) hist[i] = 0;
    __syncthreads();
    const int e0 = blockIdx.x * EPB;
#pragma unroll
    for (int it = 0; it < EPB / 256; ++it) {
        int e = e0 + it * 256 + tid;
        if (e < E) atomicAdd(&hist[dst[e] >> 7], 1);
    }
    __syncthreads();
    int* row = mat + (size_t)blockIdx.x * NB;
    for (int i = tid; i < NB; i += 256) row[i] = hist[i];
}

__global__ __launch_bounds__(512) void s2_colscan(int* __restrict__ mat,
                                                  int* __restrict__ tot, int nblk)
{
    __shared__ int ts[512];
    const int tid = threadIdx.x;
    const int b = blockIdx.x;
    int v = (tid < nblk) ? mat[(size_t)tid * NB + b] : 0;
    ts[tid] = v;
    __syncthreads();
#pragma unroll
    for (int off = 1; off < 512; off <<= 1) {
        int add = (tid >= off) ? ts[tid - off] : 0;
        __syncthreads();
        ts[tid] += add;
        __syncthreads();
    }
    if (tid < nblk) mat[(size_t)tid * NB + b] = ts[tid] - v;
    if (tid == 511) tot[b] = ts[511];
}

__global__ __launch_bounds__(NB) void s2b_base(const int* __restrict__ tot,
                                               int* __restrict__ bb,
                                               int* __restrict__ row_ptr,
                                               int N, int E)
{
    __shared__ int ts[NB];
    const int tid = threadIdx.x;
    int v = tot[tid];
    ts[tid] = v;
    __syncthreads();
#pragma unroll
    for (int off = 1; off < NB; off <<= 1) {
        int add = (tid >= off) ? ts[tid - off] : 0;
        __syncthreads();
        ts[tid] += add;
        __syncthreads();
    }
    bb[tid] = ts[tid] - v;
    if (tid == NB - 1) { bb[NB] = ts[NB - 1]; row_ptr[N] = E; }
}

__global__ __launch_bounds__(256) void s3_scatter(const int* __restrict__ src,
                                                  const int* __restrict__ dst,
                                                  const int* __restrict__ mat,
                                                  const int* __restrict__ bb,
                                                  unsigned* __restrict__ coarse, int E)
{
    __shared__ int cur[NB];
    const int tid = threadIdx.x;
    const int* mrow = mat + (size_t)blockIdx.x * NB;
    for (int i = tid; i < NB; i += 256) cur[i] = bb[i] + mrow[i];
    __syncthreads();
    const int e0 = blockIdx.x * EPB;
#pragma unroll
    for (int it = 0; it < EPB / 256; ++it) {
        int e = e0 + it * 256 + tid;
        if (e < E) {
            int d = dst[e];
            int p = atomicAdd(&cur[d >> 7], 1);
            coarse[p] = ((unsigned)src[e] << 7) | (unsigned)(d & 127);
        }
    }
}

__global__ __launch_bounds__(256) void s4_fine(const unsigned* __restrict__ coarse,
                                               const int* __restrict__ bb,
                                               int* __restrict__ row_ptr,
                                               int* __restrict__ srcs, int N)
{
    __shared__ int fcnt[128];
    __shared__ int fs[128];
    __shared__ int cur[128];
    const int tid = threadIdx.x;
    const int b = blockIdx.x;
    const int seg0 = bb[b], seg1 = bb[b + 1];
    if (tid < 128) fcnt[tid] = 0;
    __syncthreads();
    for (int p = seg0 + tid; p < seg1; p += 256)
        atomicAdd(&fcnt[coarse[p] & 127u], 1);
    __syncthreads();
    if (tid < 128) fs[tid] = fcnt[tid];
    __syncthreads();
#pragma unroll
    for (int off = 1; off < 128; off <<= 1) {
        int add = 0;
        if (tid < 128 && tid >= off) add = fs[tid - off];
        __syncthreads();
        if (tid < 128) fs[tid] += add;
        __syncthreads();
    }
    if (tid < 128) {
        int excl = fs[tid] - fcnt[tid];
        cur[tid] = seg0 + excl;
        int d = b * 128 + tid;
        if (d < N) row_ptr[d] = seg0 + excl;
    }
    __syncthreads();
    for (int p = seg0 + tid; p < seg1; p += 256) {
        unsigned v = coarse[p];
        int q = atomicAdd(&cur[v & 127u], 1);
        srcs[q] = (int)(v >> 7);
    }
}

// --------------------------- pull kernels ----------------------------------
// XCD-sliced pull: slice s = blockIdx&7 (round-robin block->XCD => each XCD
// gathers only from its 3.2MB slice). Wave = 2 nodes x 8 edge-slots x 4 lanes
// (8B each). 16-edge unroll; 3-round shfl_xor reduction within each half.
__global__ __launch_bounds__(256) void pull_sliced(const uint2* __restrict__ xs2,
                                                   const int* __restrict__ row_ptr,
                                                   const int* __restrict__ srcs,
                                                   uint2* __restrict__ aggs2, int N)
{
    const int s    = blockIdx.x & 7;
    const int wq   = threadIdx.x >> 6;              // wave in block
    const int l    = threadIdx.x & 63;
    const int hn   = l >> 5;                        // node within pair
    const int slot = (l >> 2) & 7;                  // edge slot
    const int fl   = l & 3;                         // uint2 col (feats fl*4..+4)
    const int pair = (blockIdx.x >> 3) * 4 + wq;
    const int n0   = pair * 2 + hn;
    const uint2* base = xs2 + (size_t)s * N * 4;

    int beg = 0, end = 0;
    if (n0 < N) { beg = row_ptr[n0]; end = row_ptr[n0 + 1]; }
    float a0 = 0.f, a1 = 0.f, a2 = 0.f, a3 = 0.f;
    int j = beg;
    for (; j + 15 < end; j += 16) {
        int s0 = srcs[j + slot], s1 = srcs[j + 8 + slot];
        uint2 u0 = base[(size_t)s0 * 4 + fl];
        uint2 u1 = base[(size_t)s1 * 4 + fl];
        float2 p;
        p = h2f(u0.x); a0 += p.x; a1 += p.y;  p = h2f(u0.y); a2 += p.x; a3 += p.y;
        p = h2f(u1.x); a0 += p.x; a1 += p.y;  p = h2f(u1.y); a2 += p.x; a3 += p.y;
    }
    for (; j < end; j += 8) {
        int jj = j + slot;
        float m = (jj < end) ? 1.f : 0.f;
        int s0 = srcs[(jj < end) ? jj : (end - 1)];
        uint2 u = base[(size_t)s0 * 4 + fl];
        float2 p;
        p = h2f(u.x); a0 += m * p.x; a1 += m * p.y;
        p = h2f(u.y); a2 += m * p.x; a3 += m * p.y;
    }
    // reduce over 8 slots (xor 4,8,16 stays within the 32-lane half)
    a0 += __shfl_xor(a0, 4);  a1 += __shfl_xor(a1, 4);
    a2 += __shfl_xor(a2, 4);  a3 += __shfl_xor(a3, 4);
    a0 += __shfl_xor(a0, 8);  a1 += __shfl_xor(a1, 8);
    a2 += __shfl_xor(a2, 8);  a3 += __shfl_xor(a3, 8);
    a0 += __shfl_xor(a0, 16); a1 += __shfl_xor(a1, 16);
    a2 += __shfl_xor(a2, 16); a3 += __shfl_xor(a3, 16);
    if (slot == 0 && n0 < N) {
        uint2 o; o.x = f2h(a0, a1); o.y = f2h(a2, a3);
        aggs2[(size_t)s * N * 4 + (size_t)n0 * 4 + fl] = o;
    }
}

// one wave per node. lane = (q, col): q = edge-of-quad, col = uint2 col (16/row).
// Per VMEM instr: 4 rows x 128B. Main loop = 8 edges (2 quad loads in flight).
__global__ __launch_bounds__(256) void pull_add_h64(const uint2* __restrict__ hr4,
                                                    const int* __restrict__ row_ptr,
                                                    const int* __restrict__ srcs,
                                                    float* __restrict__ out, int N)
{
    const int w   = (blockIdx.x * 256 + threadIdx.x) >> 6;
    const int l   = threadIdx.x & 63;
    const int q   = l >> 4;         // which edge of the quad
    const int col = l & 15;         // uint2 col -> feats 4c..4c+3
    if (w >= N) return;
    const int beg = row_ptr[w], end = row_ptr[w + 1];
    float a0 = 0.f, a1 = 0.f, a2 = 0.f, a3 = 0.f;
    int j = beg;
    for (; j + 7 < end; j += 8) {
        int s0 = srcs[j + q], s1 = srcs[j + 4 + q];
        uint2 u0 = hr4[(size_t)s0 * 16 + col];
        uint2 u1 = hr4[(size_t)s1 * 16 + col];
        float2 p;
        p = h2f(u0.x); a0 += p.x; a1 += p.y;  p = h2f(u0.y); a2 += p.x; a3 += p.y;
        p = h2f(u1.x); a0 += p.x; a1 += p.y;  p = h2f(u1.y); a2 += p.x; a3 += p.y;
    }
    for (; j < end; j += 4) {                      // quad tail, predicated
        int jj = j + q;
        float m = (jj < end) ? 1.f : 0.f;
        int s = srcs[(jj < end) ? jj : (end - 1)];
        uint2 u = hr4[(size_t)s * 16 + col];
        float2 p;
        p = h2f(u.x); a0 += m * p.x; a1 += m * p.y;
        p = h2f(u.y); a2 += m * p.x; a3 += m * p.y;
    }
    // combine the four quads
    a0 += __shfl_xor(a0, 16); a1 += __shfl_xor(a1, 16);
    a2 += __shfl_xor(a2, 16); a3 += __shfl_xor(a3, 16);
    a0 += __shfl_xor(a0, 32); a1 += __shfl_xor(a1, 32);
    a2 += __shfl_xor(a2, 32); a3 += __shfl_xor(a3, 32);
    if (q == 0) {
        f4* po = (f4*)out + (size_t)w * 16 + col;
        f4 cur = *po;
        cur[0] += a0; cur[1] += a1; cur[2] += a2; cur[3] += a3;
        *po = cur;
    }
}

// ----------------------- MFMA GEMM 1 (K=256 dual) --------------------------
// h(row-major) = relu([aggs|xs] @ [Wr1|Wq1]^T + b1); A tensors SLICE-MAJOR:
// elem (r, k) at A[ (k>>4)*N*16 + r*16 + (k&15) ].
__global__ __launch_bounds__(256) void mfma_gemm1(
    const _Float16* __restrict__ aggs, const _Float16* __restrict__ xs,
    const _Float16* __restrict__ wb,   // wr1h @0, wq1h @16384
    const float* __restrict__ b1,
    _Float16* __restrict__ h, int N)
{
    const int w  = threadIdx.x >> 6;
    const int l  = threadIdx.x & 63;
    const int lr = l & 15;
    const int kg = l >> 4;
    const int base = blockIdx.x * 128 + w * 32;
    const int r0 = min(base + lr,      N - 1);
    const int r1 = min(base + 16 + lr, N - 1);

    f4 acc[2][8];
#pragma unroll
    for (int s = 0; s < 2; ++s)
#pragma unroll
        for (int n = 0; n < 8; ++n) acc[s][n] = 0.f;

#pragma unroll 1
    for (int kk = 0; kk < 8; ++kk) {
        const _Float16* A = (kk < 4) ? aggs : xs;
        const _Float16* B = (kk < 4) ? wb : (wb + 16384);
        const int k0 = (kk & 3) * 32 + kg * 8;
        const size_t sbase = (size_t)(k0 >> 4) * N * 16 + (k0 & 15);
        h8 a0 = *(const h8*)(A + sbase + (size_t)r0 * 16);
        h8 a1 = *(const h8*)(A + sbase + (size_t)r1 * 16);
#pragma unroll
        for (int n = 0; n < 8; ++n) {
            h8 bf = *(const h8*)(B + (size_t)(n * 16 + lr) * 128 + k0);
            acc[0][n] = __builtin_amdgcn_mfma_f32_16x16x32_f16(a0, bf, acc[0][n], 0, 0, 0);
            acc[1][n] = __builtin_amdgcn_mfma_f32_16x16x32_f16(a1, bf, acc[1][n], 0, 0, 0);
        }
    }

    const int ro = kg * 4;   // D: row = (l>>4)*4 + j, col = l&15
#pragma unroll
    for (int s = 0; s < 2; ++s)
#pragma unroll
        for (int n = 0; n < 8; ++n) {
            const int col = n * 16 + lr;
            const float bias = b1[col];
#pragma unroll
            for (int j = 0; j < 4; ++j) {
                int r = base + s * 16 + ro + j;
                if (r < N)
                    h[(size_t)r * 128 + col] = (_Float16)fmaxf(acc[s][n][j] + bias, 0.f);
            }
        }
}

// ----------------------- MFMA GEMM 2 (K=128 split) -------------------------
// cols 0..63 -> hr(f16) = h@Wr2^T ; cols 64..127 -> out(f32) = h@Wq2^T + b2
__global__ __launch_bounds__(256) void mfma_gemm2(
    const _Float16* __restrict__ h,
    const _Float16* __restrict__ wb2,  // wr2h @0, wq2h @8192 (contiguous 128x128)
    const float* __restrict__ b2,
    _Float16* __restrict__ hrh, float* __restrict__ outp, int N)
{
    const int w  = threadIdx.x >> 6;
    const int l  = threadIdx.x & 63;
    const int lr = l & 15;
    const int kg = l >> 4;
    const int base = blockIdx.x * 128 + w * 32;
    const int r0 = min(base + lr,      N - 1);
    const int r1 = min(base + 16 + lr, N - 1);

    f4 acc[2][8];
#pragma unroll
    for (int s = 0; s < 2; ++s)
#pragma unroll
        for (int n = 0; n < 8; ++n) acc[s][n] = 0.f;

#pragma unroll 1
    for (int kk = 0; kk < 4; ++kk) {
        const int k0 = kk * 32 + kg * 8;
        h8 a0 = *(const h8*)(h + (size_t)r0 * 128 + k0);
        h8 a1 = *(const h8*)(h + (size_t)r1 * 128 + k0);
#pragma unroll
        for (int n = 0; n < 8; ++n) {
            h8 bf = *(const h8*)(wb2 + (size_t)(n * 16 + lr) * 128 + k0);
            acc[0][n] = __builtin_amdgcn_mfma_f32_16x16x32_f16(a0, bf, acc[0][n], 0, 0, 0);
            acc[1][n] = __builtin_amdgcn_mfma_f32_16x16x32_f16(a1, bf, acc[1][n], 0, 0, 0);
        }
    }

    const int ro = kg * 4;
#pragma unroll
    for (int s = 0; s < 2; ++s)
#pragma unroll
        for (int n = 0; n < 8; ++n) {
            const int col = n * 16 + lr;
#pragma unroll
            for (int j = 0; j < 4; ++j) {
                int r = base + s * 16 + ro + j;
                if (r < N) {
                    if (n < 4) {
                        hrh[(size_t)r * 64 + col] = (_Float16)acc[s][n][j];
                    } else {
                        outp[(size_t)r * 64 + (col - 64)] = acc[s][n][j] + b2[col - 64];
                    }
                }
            }
        }
}

extern "C" void kernel_launch(void* const* d_in, const int* in_sizes, int n_in,
                              void* d_out, int out_size, void* d_ws, size_t ws_size,
                              hipStream_t stream)
{
    const float* x       = (const float*)d_in[0];
    const int*   ei      = (const int*)d_in[1];
    const float* w_rel1  = (const float*)d_in[2];
    const float* b_rel1  = (const float*)d_in[3];
    const float* w_root1 = (const float*)d_in[4];
    const float* w_rel2  = (const float*)d_in[5];
    const float* b_rel2  = (const float*)d_in[6];
    const float* w_root2 = (const float*)d_in[7];
    float* out = (float*)d_out;

    const int N = in_sizes[0] / 128;
    const int E = in_sizes[1] / 2;
    const int* src = ei;        // edge_index[0]
    const int* dst = ei + E;    // edge_index[1]

    // workspace (~92 MB):
    //   xs [8][N][16] h | aggs [8][N][16] h (hrh aliases) | hbuf [N*128 h]
    //   | wbuf [49152 h] | srcs [E] | coarse [E u32] | mat [nblk*NB]
    //   | tot [NB] | bb [NB+1] | row_ptr [N+1]
    _Float16* xs    = (_Float16*)d_ws;
    _Float16* aggs  = xs + (size_t)N * 128;
    _Float16* hbuf  = aggs + (size_t)N * 128;
    _Float16* hrh   = aggs;                         // alias: aggs dead after gemm1
    _Float16* wbuf  = hbuf + (size_t)N * 128;
    int*      srcs    = (int*)(wbuf + 49152);
    unsigned* coarse  = (unsigned*)(srcs + E);
    const int nblk    = (E + EPB - 1) / EPB;        // <= 512 (E <= 2M)
    int*      mat     = (int*)(coarse + E);         // nblk*NB
    int*      tot     = mat + (size_t)nblk * NB;    // NB
    int*      bb      = tot + NB;                   // NB+1
    int*      row_ptr = bb + (NB + 1);              // N+1

    // ---- f16 staging ----
    wcast<<<(49152 + 255) / 256, 256, 0, stream>>>(w_rel1, w_root1, w_rel2, w_root2, wbuf);
    xcast_sliced<<<(int)(((long)N * 8 + 255) / 256), 256, 0, stream>>>(x, xs, N);

    // ---- CSR build: atomic-free 2-level counting sort ----
    s1_hist   <<<nblk, 256, 0, stream>>>(dst, mat, E);
    s2_colscan<<<NB, 512, 0, stream>>>(mat, tot, nblk);
    s2b_base  <<<1, NB, 0, stream>>>(tot, bb, row_ptr, N, E);
    s3_scatter<<<nblk, 256, 0, stream>>>(src, dst, mat, bb, coarse, E);
    s4_fine   <<<NB, 256, 0, stream>>>(coarse, bb, row_ptr, srcs, N);

    // 1. aggs = pull-sum xs (XCD-sliced)
    {
        int pairs = (N + 1) / 2;
        int pblocks = ((pairs + 3) / 4) * 8;        // 4 pairs/block, 8 slices
        pull_sliced<<<pblocks, 256, 0, stream>>>(
            (const uint2*)xs, row_ptr, srcs, (uint2*)aggs, N);
    }

    // 2/3. MFMA GEMMs
    {
        int grid = (N + 127) / 128;
        mfma_gemm1<<<grid, 256, 0, stream>>>(aggs, xs, wbuf, b_rel1, hbuf, N);
        mfma_gemm2<<<grid, 256, 0, stream>>>(hbuf, wbuf + 32768, b_rel2, hrh, out, N);
    }

    // 4. out += pull-sum hr
    pull_add_h64<<<(N * 64 + 255) / 256, 256, 0, stream>>>(
        (const uint2*)hrh, row_ptr, srcs, out, N);
}

// Round 14
// 241.944 us; speedup vs baseline: 1.3330x; 1.3330x over previous
//
#include <hip/hip_runtime.h>

// GraphConv x2, CSR-pull + FUSED f16 MFMA GEMMs (R13 resubmit; R13 bench died
// to an unresponsive container):
//   wcast/xcast -> f16 staging (row-major, R9 layout)
//   CSR build: atomic-free 2-level counting sort (R11, unchanged)
//   pull_h128: aggh = sum xh[srcs]          (R9 version, 62us = gather BW floor)
//   mfma_fused: h = relu(aggh@Wr1^T + xh@Wq1^T + b1)  [regs]
//               -> LDS (XOR-swizzled per-wave 32x128 tile) ->
//               hr(f16) = h@Wr2^T ; out(f32) = h@Wq2^T + b2
//   pull_add_h64: out += sum hr[srcs]       (R9 version)
//
// R13 rationale: R12's slicing halved gather granularity to 32B (half a line)
// -> 2x line fetches -> 127us. REVERTED (62us version ~= 6.6 TB/s delivered,
// at the mixed-path ceiling). New lever: gemm1's wave computes exactly the 32
// rows gemm2's wave consumes -> fuse via per-wave LDS transpose (swizzled),
// deleting the 51 MB h-buffer roundtrip and one launch.

typedef float f4 __attribute__((ext_vector_type(4)));
typedef _Float16 h8 __attribute__((ext_vector_type(8)));
typedef _Float16 h2 __attribute__((ext_vector_type(2)));

#define NB   1024    // coarse buckets (dst>>7); requires N <= 131072
#define EPB  4096    // edges per block in s1/s3; nblk = ceil(E/EPB) <= 512

__device__ __forceinline__ float2 h2f(unsigned u) {
    h2 p = __builtin_bit_cast(h2, u);
    float2 r; r.x = (float)p[0]; r.y = (float)p[1];
    return r;
}
__device__ __forceinline__ unsigned f2h(float a, float b) {
    h2 p; p[0] = (_Float16)a; p[1] = (_Float16)b;
    return __builtin_bit_cast(unsigned, p);
}

// ---------------------------- casts ----------------------------------------
// wbuf layout (halves): wr1h @0 [128x128] | wq1h @16384 | wr2h @32768 [64x128]
// | wq2h @40960  (total 49152)
__global__ void wcast(const float* __restrict__ wr1, const float* __restrict__ wq1,
                      const float* __restrict__ wr2, const float* __restrict__ wq2,
                      _Float16* __restrict__ wb)
{
    int i = blockIdx.x * 256 + threadIdx.x;
    if (i < 16384)      wb[i] = (_Float16)wr1[i];
    else if (i < 32768) wb[i] = (_Float16)wq1[i - 16384];
    else if (i < 40960) wb[i] = (_Float16)wr2[i - 32768];
    else if (i < 49152) wb[i] = (_Float16)wq2[i - 40960];
}

__global__ void xcast(const float* __restrict__ x, _Float16* __restrict__ xh,
                      long n)   // n = N*128, multiple of 8
{
    long i = (long)(blockIdx.x * 256 + threadIdx.x) * 8;
    if (i >= n) return;
    f4 a = *(const f4*)(x + i);
    f4 b = *(const f4*)(x + i + 4);
    h8 o;
    o[0] = (_Float16)a[0]; o[1] = (_Float16)a[1];
    o[2] = (_Float16)a[2]; o[3] = (_Float16)a[3];
    o[4] = (_Float16)b[0]; o[5] = (_Float16)b[1];
    o[6] = (_Float16)b[2]; o[7] = (_Float16)b[3];
    *(h8*)(xh + i) = o;
}

// ------------------ CSR build: atomic-free counting sort --------------------
__global__ __launch_bounds__(256) void s1_hist(const int* __restrict__ dst,
                                               int* __restrict__ mat, int E)
{
    __shared__ int hist[NB];
    const int tid = threadIdx.x;
    for (int i = tid; i < NB; i += 256) hist[i] = 0;
    __syncthreads();
    const int e0 = blockIdx.x * EPB;
#pragma unroll
    for (int it = 0; it < EPB / 256; ++it) {
        int e = e0 + it * 256 + tid;
        if (e < E) atomicAdd(&hist[dst[e] >> 7], 1);
    }
    __syncthreads();
    int* row = mat + (size_t)blockIdx.x * NB;
    for (int i = tid; i < NB; i += 256) row[i] = hist[i];
}

__global__ __launch_bounds__(512) void s2_colscan(int* __restrict__ mat,
                                                  int* __restrict__ tot, int nblk)
{
    __shared__ int ts[512];
    const int tid = threadIdx.x;
    const int b = blockIdx.x;
    int v = (tid < nblk) ? mat[(size_t)tid * NB + b] : 0;
    ts[tid] = v;
    __syncthreads();
#pragma unroll
    for (int off = 1; off < 512; off <<= 1) {
        int add = (tid >= off) ? ts[tid - off] : 0;
        __syncthreads();
        ts[tid] += add;
        __syncthreads();
    }
    if (tid < nblk) mat[(size_t)tid * NB + b] = ts[tid] - v;
    if (tid == 511) tot[b] = ts[511];
}

__global__ __launch_bounds__(NB) void s2b_base(const int* __restrict__ tot,
                                               int* __restrict__ bb,
                                               int* __restrict__ row_ptr,
                                               int N, int E)
{
    __shared__ int ts[NB];
    const int tid = threadIdx.x;
    int v = tot[tid];
    ts[tid] = v;
    __syncthreads();
#pragma unroll
    for (int off = 1; off < NB; off <<= 1) {
        int add = (tid >= off) ? ts[tid - off] : 0;
        __syncthreads();
        ts[tid] += add;
        __syncthreads();
    }
    bb[tid] = ts[tid] - v;
    if (tid == NB - 1) { bb[NB] = ts[NB - 1]; row_ptr[N] = E; }
}

__global__ __launch_bounds__(256) void s3_scatter(const int* __restrict__ src,
                                                  const int* __restrict__ dst,
                                                  const int* __restrict__ mat,
                                                  const int* __restrict__ bb,
                                                  unsigned* __restrict__ coarse, int E)
{
    __shared__ int cur[NB];
    const int tid = threadIdx.x;
    const int* mrow = mat + (size_t)blockIdx.x * NB;
    for (int i = tid; i < NB; i += 256) cur[i] = bb[i] + mrow[i];
    __syncthreads();
    const int e0 = blockIdx.x * EPB;
#pragma unroll
    for (int it = 0; it < EPB / 256; ++it) {
        int e = e0 + it * 256 + tid;
        if (e < E) {
            int d = dst[e];
            int p = atomicAdd(&cur[d >> 7], 1);
            coarse[p] = ((unsigned)src[e] << 7) | (unsigned)(d & 127);
        }
    }
}

__global__ __launch_bounds__(256) void s4_fine(const unsigned* __restrict__ coarse,
                                               const int* __restrict__ bb,
                                               int* __restrict__ row_ptr,
                                               int* __restrict__ srcs, int N)
{
    __shared__ int fcnt[128];
    __shared__ int fs[128];
    __shared__ int cur[128];
    const int tid = threadIdx.x;
    const int b = blockIdx.x;
    const int seg0 = bb[b], seg1 = bb[b + 1];
    if (tid < 128) fcnt[tid] = 0;
    __syncthreads();
    for (int p = seg0 + tid; p < seg1; p += 256)
        atomicAdd(&fcnt[coarse[p] & 127u], 1);
    __syncthreads();
    if (tid < 128) fs[tid] = fcnt[tid];
    __syncthreads();
#pragma unroll
    for (int off = 1; off < 128; off <<= 1) {
        int add = 0;
        if (tid < 128 && tid >= off) add = fs[tid - off];
        __syncthreads();
        if (tid < 128) fs[tid] += add;
        __syncthreads();
    }
    if (tid < 128) {
        int excl = fs[tid] - fcnt[tid];
        cur[tid] = seg0 + excl;
        int d = b * 128 + tid;
        if (d < N) row_ptr[d] = seg0 + excl;
    }
    __syncthreads();
    for (int p = seg0 + tid; p < seg1; p += 256) {
        unsigned v = coarse[p];
        int q = atomicAdd(&cur[v & 127u], 1);
        srcs[q] = (int)(v >> 7);
    }
}

// --------------------------- pull kernels (R9 versions) ---------------------
// one wave per node. lane = (half, col): half = edge-of-pair, col = uint2 col.
__global__ __launch_bounds__(256) void pull_h128(const uint2* __restrict__ xh4,
                                                 const int* __restrict__ row_ptr,
                                                 const int* __restrict__ srcs,
                                                 uint2* __restrict__ aggh4, int N)
{
    const int w    = (blockIdx.x * 256 + threadIdx.x) >> 6;
    const int l    = threadIdx.x & 63;
    const int half = l >> 5;
    const int col  = l & 31;
    if (w >= N) return;
    const int beg = row_ptr[w], end = row_ptr[w + 1];
    float a0 = 0.f, a1 = 0.f, a2 = 0.f, a3 = 0.f;
    int j = beg;
    for (; j + 7 < end; j += 8) {
        int s0 = srcs[j + 0 + half], s1 = srcs[j + 2 + half];
        int s2 = srcs[j + 4 + half], s3 = srcs[j + 6 + half];
        uint2 u0 = xh4[(size_t)s0 * 32 + col];
        uint2 u1 = xh4[(size_t)s1 * 32 + col];
        uint2 u2 = xh4[(size_t)s2 * 32 + col];
        uint2 u3 = xh4[(size_t)s3 * 32 + col];
        float2 p;
        p = h2f(u0.x); a0 += p.x; a1 += p.y;  p = h2f(u0.y); a2 += p.x; a3 += p.y;
        p = h2f(u1.x); a0 += p.x; a1 += p.y;  p = h2f(u1.y); a2 += p.x; a3 += p.y;
        p = h2f(u2.x); a0 += p.x; a1 += p.y;  p = h2f(u2.y); a2 += p.x; a3 += p.y;
        p = h2f(u3.x); a0 += p.x; a1 += p.y;  p = h2f(u3.y); a2 += p.x; a3 += p.y;
    }
    for (; j < end; j += 2) {
        int jj = j + half;
        float m = (jj < end) ? 1.f : 0.f;
        int s = srcs[(jj < end) ? jj : (end - 1)];
        uint2 u = xh4[(size_t)s * 32 + col];
        float2 p;
        p = h2f(u.x); a0 += m * p.x; a1 += m * p.y;
        p = h2f(u.y); a2 += m * p.x; a3 += m * p.y;
    }
    a0 += __shfl_xor(a0, 32); a1 += __shfl_xor(a1, 32);
    a2 += __shfl_xor(a2, 32); a3 += __shfl_xor(a3, 32);
    if (half == 0) {
        uint2 o; o.x = f2h(a0, a1); o.y = f2h(a2, a3);
        aggh4[(size_t)w * 32 + col] = o;
    }
}

// one wave per node. lane = (q, col): q = edge-of-quad, col = uint2 col (16/row).
__global__ __launch_bounds__(256) void pull_add_h64(const uint2* __restrict__ hr4,
                                                    const int* __restrict__ row_ptr,
                                                    const int* __restrict__ srcs,
                                                    float* __restrict__ out, int N)
{
    const int w   = (blockIdx.x * 256 + threadIdx.x) >> 6;
    const int l   = threadIdx.x & 63;
    const int q   = l >> 4;
    const int col = l & 15;
    if (w >= N) return;
    const int beg = row_ptr[w], end = row_ptr[w + 1];
    float a0 = 0.f, a1 = 0.f, a2 = 0.f, a3 = 0.f;
    int j = beg;
    for (; j + 7 < end; j += 8) {
        int s0 = srcs[j + q], s1 = srcs[j + 4 + q];
        uint2 u0 = hr4[(size_t)s0 * 16 + col];
        uint2 u1 = hr4[(size_t)s1 * 16 + col];
        float2 p;
        p = h2f(u0.x); a0 += p.x; a1 += p.y;  p = h2f(u0.y); a2 += p.x; a3 += p.y;
        p = h2f(u1.x); a0 += p.x; a1 += p.y;  p = h2f(u1.y); a2 += p.x; a3 += p.y;
    }
    for (; j < end; j += 4) {
        int jj = j + q;
        float m = (jj < end) ? 1.f : 0.f;
        int s = srcs[(jj < end) ? jj : (end - 1)];
        uint2 u = hr4[(size_t)s * 16 + col];
        float2 p;
        p = h2f(u.x); a0 += m * p.x; a1 += m * p.y;
        p = h2f(u.y); a2 += m * p.x; a3 += m * p.y;
    }
    a0 += __shfl_xor(a0, 16); a1 += __shfl_xor(a1, 16);
    a2 += __shfl_xor(a2, 16); a3 += __shfl_xor(a3, 16);
    a0 += __shfl_xor(a0, 32); a1 += __shfl_xor(a1, 32);
    a2 += __shfl_xor(a2, 32); a3 += __shfl_xor(a3, 32);
    if (q == 0) {
        f4* po = (f4*)out + (size_t)w * 16 + col;
        f4 cur = *po;
        cur[0] += a0; cur[1] += a1; cur[2] += a2; cur[3] += a3;
        *po = cur;
    }
}

// ----------------------- FUSED MFMA GEMM (layer1 + layer2) ------------------
// Per block: 128 rows. Per wave: 32 rows, all 128 cols.
//   gemm1: acc = [aggh|xh] @ [Wr1|Wq1]^T  (K=256 dual), relu+bias -> LDS tile
//   (per-wave 32x128 f16, XOR-swizzled: f16idx = col ^ ((row&7)<<3))
//   gemm2: A-frags from LDS; cols 0..63 -> hr(f16), 64..127 -> out(f32)+b2
__global__ __launch_bounds__(256) void mfma_fused(
    const _Float16* __restrict__ aggh, const _Float16* __restrict__ xh,
    const _Float16* __restrict__ wb,   // wr1h@0, wq1h@16384, wr2h@32768, wq2h@40960
    const float* __restrict__ b1, const float* __restrict__ b2,
    _Float16* __restrict__ hrh, float* __restrict__ outp, int N)
{
    __shared__ _Float16 hs[4][32 * 128];   // 32 KB, per-wave private tiles
    const int w  = threadIdx.x >> 6;
    const int l  = threadIdx.x & 63;
    const int lr = l & 15;
    const int kg = l >> 4;
    const int base = blockIdx.x * 128 + w * 32;
    const int r0 = min(base + lr,      N - 1);
    const int r1 = min(base + 16 + lr, N - 1);
    _Float16* hb = &hs[w][0];

    f4 acc[2][8];
#pragma unroll
    for (int s = 0; s < 2; ++s)
#pragma unroll
        for (int n = 0; n < 8; ++n) acc[s][n] = 0.f;

    // ---- layer 1: K=256 dual ----
#pragma unroll 1
    for (int kk = 0; kk < 8; ++kk) {
        const _Float16* A = (kk < 4) ? aggh : xh;
        const _Float16* B = (kk < 4) ? wb : (wb + 16384);
        const int k0 = (kk & 3) * 32 + kg * 8;
        h8 a0 = *(const h8*)(A + (size_t)r0 * 128 + k0);
        h8 a1 = *(const h8*)(A + (size_t)r1 * 128 + k0);
#pragma unroll
        for (int n = 0; n < 8; ++n) {
            h8 bf = *(const h8*)(B + (size_t)(n * 16 + lr) * 128 + k0);
            acc[0][n] = __builtin_amdgcn_mfma_f32_16x16x32_f16(a0, bf, acc[0][n], 0, 0, 0);
            acc[1][n] = __builtin_amdgcn_mfma_f32_16x16x32_f16(a1, bf, acc[1][n], 0, 0, 0);
        }
    }

    // ---- relu+bias -> swizzled LDS tile (rows local to this wave) ----
    const int ro = kg * 4;
#pragma unroll
    for (int s = 0; s < 2; ++s)
#pragma unroll
        for (int n = 0; n < 8; ++n) {
            const int col = n * 16 + lr;
            const float bias = b1[col];
#pragma unroll
            for (int j = 0; j < 4; ++j) {
                const int row = s * 16 + ro + j;
                hb[row * 128 + (col ^ ((row & 7) << 3))] =
                    (_Float16)fmaxf(acc[s][n][j] + bias, 0.f);
            }
        }
    __syncthreads();   // (per-wave private, but cheap and safe)

    // ---- layer 2: K=128 from LDS ----
    f4 acc2[2][8];
#pragma unroll
    for (int s = 0; s < 2; ++s)
#pragma unroll
        for (int n = 0; n < 8; ++n) acc2[s][n] = 0.f;

#pragma unroll
    for (int kk = 0; kk < 4; ++kk) {
        const int k0 = kk * 32 + kg * 8;
        const int swz = (lr & 7) << 3;             // row&7 == lr&7 for both halves
        h8 a0 = *(const h8*)&hb[lr * 128 + (k0 ^ swz)];
        h8 a1 = *(const h8*)&hb[(16 + lr) * 128 + (k0 ^ swz)];
#pragma unroll
        for (int n = 0; n < 8; ++n) {
            h8 bf = *(const h8*)(wb + 32768 + (size_t)(n * 16 + lr) * 128 + k0);
            acc2[0][n] = __builtin_amdgcn_mfma_f32_16x16x32_f16(a0, bf, acc2[0][n], 0, 0, 0);
            acc2[1][n] = __builtin_amdgcn_mfma_f32_16x16x32_f16(a1, bf, acc2[1][n], 0, 0, 0);
        }
    }

#pragma unroll
    for (int s = 0; s < 2; ++s)
#pragma unroll
        for (int n = 0; n < 8; ++n) {
            const int col = n * 16 + lr;
#pragma unroll
            for (int j = 0; j < 4; ++j) {
                int r = base + s * 16 + ro + j;
                if (r < N) {
                    if (n < 4) {
                        hrh[(size_t)r * 64 + col] = (_Float16)acc2[s][n][j];
                    } else {
                        outp[(size_t)r * 64 + (col - 64)] = acc2[s][n][j] + b2[col - 64];
                    }
                }
            }
        }
}

extern "C" void kernel_launch(void* const* d_in, const int* in_sizes, int n_in,
                              void* d_out, int out_size, void* d_ws, size_t ws_size,
                              hipStream_t stream)
{
    const float* x       = (const float*)d_in[0];
    const int*   ei      = (const int*)d_in[1];
    const float* w_rel1  = (const float*)d_in[2];
    const float* b_rel1  = (const float*)d_in[3];
    const float* w_root1 = (const float*)d_in[4];
    const float* w_rel2  = (const float*)d_in[5];
    const float* b_rel2  = (const float*)d_in[6];
    const float* w_root2 = (const float*)d_in[7];
    float* out = (float*)d_out;

    const int N = in_sizes[0] / 128;
    const int E = in_sizes[1] / 2;
    const int* src = ei;        // edge_index[0]
    const int* dst = ei + E;    // edge_index[1]

    // workspace (~67 MB):
    //   xh [N*128 h] | aggh [N*128 h] (hrh aliases) | wbuf [49152 h]
    //   | srcs [E] | coarse [E u32] | mat [nblk*NB] | tot [NB] | bb [NB+1]
    //   | row_ptr [N+1]
    _Float16* xh    = (_Float16*)d_ws;
    _Float16* aggh  = xh + (size_t)N * 128;
    _Float16* hrh   = aggh;                         // alias: aggh dead after gemm
    _Float16* wbuf  = aggh + (size_t)N * 128;
    int*      srcs    = (int*)(wbuf + 49152);
    unsigned* coarse  = (unsigned*)(srcs + E);
    const int nblk    = (E + EPB - 1) / EPB;        // <= 512 (E <= 2M)
    int*      mat     = (int*)(coarse + E);         // nblk*NB
    int*      tot     = mat + (size_t)nblk * NB;    // NB
    int*      bb      = tot + NB;                   // NB+1
    int*      row_ptr = bb + (NB + 1);              // N+1

    // ---- f16 staging ----
    wcast<<<(49152 + 255) / 256, 256, 0, stream>>>(w_rel1, w_root1, w_rel2, w_root2, wbuf);
    xcast<<<(N * 128 / 8 + 255) / 256, 256, 0, stream>>>(x, xh, (long)N * 128);

    // ---- CSR build: atomic-free 2-level counting sort ----
    s1_hist   <<<nblk, 256, 0, stream>>>(dst, mat, E);
    s2_colscan<<<NB, 512, 0, stream>>>(mat, tot, nblk);
    s2b_base  <<<1, NB, 0, stream>>>(tot, bb, row_ptr, N, E);
    s3_scatter<<<nblk, 256, 0, stream>>>(src, dst, mat, bb, coarse, E);
    s4_fine   <<<NB, 256, 0, stream>>>(coarse, bb, row_ptr, srcs, N);

    // 1. aggh = pull-sum xh
    pull_h128<<<(N * 64 + 255) / 256, 256, 0, stream>>>(
        (const uint2*)xh, row_ptr, srcs, (uint2*)aggh, N);

    // 2. fused GEMMs: hr(f16) = relu(...)@Wr2^T ; out = relu(...)@Wq2^T + b2
    mfma_fused<<<(N + 127) / 128, 256, 0, stream>>>(
        aggh, xh, wbuf, b_rel1, b_rel2, hrh, out, N);

    // 3. out += pull-sum hr
    pull_add_h64<<<(N * 64 + 255) / 256, 256, 0, stream>>>(
        (const uint2*)hrh, row_ptr, srcs, out, N);
}